// Round 2
// baseline (560.498 us; speedup 1.0000x reference)
//
#include <hip/hip_runtime.h>
#include <math.h>

#define S_LEN 2048
#define DMODEL 1024
#define NHEADS 16
#define HDIM 64
#define WIN 256
#define N_QKV 3072

typedef __attribute__((ext_vector_type(8))) short s16x8;
typedef __attribute__((ext_vector_type(4))) float f32x4;

__device__ inline unsigned short f2bf(float f) {
    unsigned int u = __float_as_uint(f);
    u += 0x7FFFu + ((u >> 16) & 1u);      // round-to-nearest-even
    return (unsigned short)(u >> 16);
}
__device__ inline float bf2f(unsigned short h) {
    return __uint_as_float(((unsigned int)h) << 16);
}

// ---------------------------------------------------------------------------
// split fp32 -> (hi, lo) bf16, elementwise.  4 floats / thread.
// ---------------------------------------------------------------------------
__global__ __launch_bounds__(256) void split_f32(
    const float* __restrict__ src, unsigned short* __restrict__ hi,
    unsigned short* __restrict__ lo)
{
    int i = blockIdx.x * 256 + threadIdx.x;
    float4 v = *(const float4*)&src[i * 4];
    ushort4 h, l;
    h.x = f2bf(v.x); l.x = f2bf(v.x - bf2f(h.x));
    h.y = f2bf(v.y); l.y = f2bf(v.y - bf2f(h.y));
    h.z = f2bf(v.z); l.z = f2bf(v.z - bf2f(h.z));
    h.w = f2bf(v.w); l.w = f2bf(v.w - bf2f(h.w));
    *(ushort4*)&hi[i * 4] = h;
    *(ushort4*)&lo[i * 4] = l;
}

// ---------------------------------------------------------------------------
// W [K][N] f32  ->  WT_hi / WT_lo [N][K] bf16   (32x32 tiles)
// ---------------------------------------------------------------------------
__global__ __launch_bounds__(256) void transpose_split(
    const float* __restrict__ W, unsigned short* __restrict__ Thi,
    unsigned short* __restrict__ Tlo, int K, int N)
{
    __shared__ float t[32][33];
    const int tx = threadIdx.x & 31;
    const int ty = threadIdx.x >> 5;          // 0..7
    const int n0 = blockIdx.x * 32, k0 = blockIdx.y * 32;

    #pragma unroll
    for (int i = 0; i < 4; ++i)
        t[ty + i * 8][tx] = W[(size_t)(k0 + ty + i * 8) * N + n0 + tx];
    __syncthreads();
    #pragma unroll
    for (int i = 0; i < 4; ++i) {
        int n = n0 + ty + i * 8;
        float v = t[tx][ty + i * 8];
        unsigned short h = f2bf(v);
        Thi[(size_t)n * K + k0 + tx] = h;
        Tlo[(size_t)n * K + k0 + tx] = f2bf(v - bf2f(h));
    }
}

// ---------------------------------------------------------------------------
// bf16x3 split-precision MFMA GEMM.
// C[M,N] = A[M,K] @ B[K,N] (+resid), A given as hi/lo bf16 [M][K] row-major,
// B given as hi/lo bf16 of B^T, i.e. [N][K] row-major.
// Error ~2^-18 relative: fp32-grade output.
// block = 256 (4 waves as 2x2), BK = 32, fragments via k-map k = 8*(lane>>4)+j
// (any consistent bijection is exact — A slot (g,j) pairs with B slot (g,j)).
// ---------------------------------------------------------------------------
template<int BM, int BN, bool RES>
__global__ __launch_bounds__(256) void gemm_bf16x3(
    const unsigned short* __restrict__ Ahi, const unsigned short* __restrict__ Alo,
    const unsigned short* __restrict__ Bhi, const unsigned short* __restrict__ Blo,
    const float* __restrict__ resid, float* __restrict__ C,
    int M, int N, int K)
{
    constexpr int P  = 40;                 // LDS pitch (bf16): 80 B, 16B-aligned rows
    constexpr int MI = 4;                  // 64/16 m-frags per wave
    constexpr int NJ = BN / 32;            // n-frags per wave

    __shared__ unsigned short As_h[BM][P], As_l[BM][P];
    __shared__ unsigned short Bs_h[BN][P], Bs_l[BN][P];

    const int tid  = threadIdx.x;
    const int w    = tid >> 6;
    const int lane = tid & 63;
    const int m16  = lane & 15;
    const int g    = lane >> 4;
    const int wr   = w >> 1, wc = w & 1;
    const int bm   = blockIdx.y * BM, bn = blockIdx.x * BN;

    f32x4 acc[MI][NJ];
    #pragma unroll
    for (int i = 0; i < MI; ++i)
        #pragma unroll
        for (int j = 0; j < NJ; ++j) acc[i][j] = (f32x4)(0.0f);

    for (int k0 = 0; k0 < K; k0 += 32) {
        __syncthreads();
        for (int f = tid; f < BM * 4; f += 256) {
            int r = f >> 2, c = (f & 3) * 8;
            *(s16x8*)&As_h[r][c] = *(const s16x8*)&Ahi[(size_t)(bm + r) * K + k0 + c];
            *(s16x8*)&As_l[r][c] = *(const s16x8*)&Alo[(size_t)(bm + r) * K + k0 + c];
        }
        for (int f = tid; f < BN * 4; f += 256) {
            int r = f >> 2, c = (f & 3) * 8;
            *(s16x8*)&Bs_h[r][c] = *(const s16x8*)&Bhi[(size_t)(bn + r) * K + k0 + c];
            *(s16x8*)&Bs_l[r][c] = *(const s16x8*)&Blo[(size_t)(bn + r) * K + k0 + c];
        }
        __syncthreads();

        s16x8 ah[MI], al[MI];
        #pragma unroll
        for (int i = 0; i < MI; ++i) {
            ah[i] = *(const s16x8*)&As_h[wr * 64 + i * 16 + m16][g * 8];
            al[i] = *(const s16x8*)&As_l[wr * 64 + i * 16 + m16][g * 8];
        }
        #pragma unroll
        for (int j = 0; j < NJ; ++j) {
            s16x8 bh = *(const s16x8*)&Bs_h[wc * (BN / 2) + j * 16 + m16][g * 8];
            s16x8 bl = *(const s16x8*)&Bs_l[wc * (BN / 2) + j * 16 + m16][g * 8];
            #pragma unroll
            for (int i = 0; i < MI; ++i) {
                acc[i][j] = __builtin_amdgcn_mfma_f32_16x16x32_bf16(ah[i], bh, acc[i][j], 0, 0, 0);
                acc[i][j] = __builtin_amdgcn_mfma_f32_16x16x32_bf16(ah[i], bl, acc[i][j], 0, 0, 0);
                acc[i][j] = __builtin_amdgcn_mfma_f32_16x16x32_bf16(al[i], bh, acc[i][j], 0, 0, 0);
            }
        }
    }

    // epilogue: C/D map (HW-verified): col = lane&15, row = 4*(lane>>4)+reg
    const int g4 = g * 4;
    #pragma unroll
    for (int i = 0; i < MI; ++i)
        #pragma unroll
        for (int j = 0; j < NJ; ++j) {
            int col = bn + wc * (BN / 2) + j * 16 + m16;
            #pragma unroll
            for (int r = 0; r < 4; ++r) {
                int row = bm + wr * 64 + i * 16 + g4 + r;
                float val = acc[i][j][r];
                if (RES) val += resid[(size_t)row * N + col];
                C[(size_t)row * N + col] = val;
            }
        }
}

// ---------------------------------------------------------------------------
// RoPE + scatter qkv[S,3072] -> q,k,v each [H][S][64] f32 (rope on q,k)
// ---------------------------------------------------------------------------
__global__ __launch_bounds__(256) void rope_scatter(
    const float* __restrict__ qkv, float* __restrict__ q,
    float* __restrict__ k, float* __restrict__ v)
{
    int idx = blockIdx.x * 256 + threadIdx.x;   // 0 .. S*D-1
    int s  = idx >> 10;
    int r  = idx & 1023;
    int hd = r & 63;
    int h  = r >> 6;
    const float* row = qkv + (size_t)s * N_QKV;

    float qv = row[r];
    float kv = row[DMODEL + r];
    float vv = row[2 * DMODEL + r];

    int   i   = hd & 31;
    float inv = expf(-(float)i * 0.2878231366242553f);   // 10000^(-i/32)
    float ang = (float)s * inv;
    float c  = cosf(ang);
    float sn = sinf(ang);

    int   pr  = (hd < 32) ? r + 32 : r - 32;
    float sgn = (hd < 32) ? -1.0f : 1.0f;

    float qo = qv * c + sgn * row[pr] * sn;
    float ko = kv * c + sgn * row[DMODEL + pr] * sn;

    size_t o = ((size_t)h * S_LEN + s) * HDIM + hd;
    q[o] = qo;
    k[o] = ko;
    v[o] = vv;
}

// ---------------------------------------------------------------------------
// Windowed causal attention. One wave per query, 16 queries per 1024-thread
// block (16x K/V L2-reuse vs 4). Output written as hi/lo bf16 for GEMM2.
// Per-wave LDS buffers -> no block barriers needed.
// ---------------------------------------------------------------------------
__global__ __launch_bounds__(1024) void attn_win(
    const float* __restrict__ q, const float* __restrict__ k,
    const float* __restrict__ v, unsigned short* __restrict__ ohi,
    unsigned short* __restrict__ olo)
{
    const int h    = blockIdx.y;
    const int wave = threadIdx.x >> 6;      // 0..15
    const int lane = threadIdx.x & 63;
    const int s    = blockIdx.x * 16 + wave;

    __shared__ float shq[16][HDIM];
    __shared__ float shp[16][WIN + 8];

    const float* qrow = q + ((size_t)h * S_LEN + s) * HDIM;
    shq[wave][lane] = qrow[lane];

    const int t0  = (s - WIN > 0) ? (s - WIN) : 0;
    const int cnt = s - t0 + 1;                 // <= 257
    const float* kbase = k + ((size_t)h * S_LEN + t0) * HDIM;

    float sc[5];
    #pragma unroll
    for (int c = 0; c < 5; ++c) {
        int ti = c * 64 + lane;
        float d = -INFINITY;
        if (ti < cnt) {
            const float* kr = kbase + (size_t)ti * HDIM;
            float acc = 0.0f;
            #pragma unroll
            for (int jq = 0; jq < 16; ++jq) {
                float4 kv4 = *(const float4*)&kr[jq * 4];
                float4 qv4 = *(const float4*)&shq[wave][jq * 4];
                acc = fmaf(kv4.x, qv4.x, acc);
                acc = fmaf(kv4.y, qv4.y, acc);
                acc = fmaf(kv4.z, qv4.z, acc);
                acc = fmaf(kv4.w, qv4.w, acc);
            }
            d = acc * 0.125f;
        }
        sc[c] = d;
    }

    float m = sc[0];
    #pragma unroll
    for (int c = 1; c < 5; ++c) m = fmaxf(m, sc[c]);
    #pragma unroll
    for (int off = 1; off < 64; off <<= 1) m = fmaxf(m, __shfl_xor(m, off));

    float p[5];
    float sum = 0.0f;
    #pragma unroll
    for (int c = 0; c < 5; ++c) {
        p[c] = (sc[c] == -INFINITY) ? 0.0f : __expf(sc[c] - m);
        sum += p[c];
    }
    #pragma unroll
    for (int off = 1; off < 64; off <<= 1) sum += __shfl_xor(sum, off);
    float isum = 1.0f / sum;

    #pragma unroll
    for (int c = 0; c < 5; ++c) {
        int ti = c * 64 + lane;
        if (ti < cnt) shp[wave][ti] = p[c] * isum;
    }

    const float* vbase = v + ((size_t)h * S_LEN + t0) * HDIM;
    float o = 0.0f;
    int ti = 0;
    for (; ti + 4 <= cnt; ti += 4) {
        o = fmaf(shp[wave][ti + 0], vbase[(size_t)(ti + 0) * HDIM + lane], o);
        o = fmaf(shp[wave][ti + 1], vbase[(size_t)(ti + 1) * HDIM + lane], o);
        o = fmaf(shp[wave][ti + 2], vbase[(size_t)(ti + 2) * HDIM + lane], o);
        o = fmaf(shp[wave][ti + 3], vbase[(size_t)(ti + 3) * HDIM + lane], o);
    }
    for (; ti < cnt; ++ti)
        o = fmaf(shp[wave][ti], vbase[(size_t)ti * HDIM + lane], o);

    size_t oi = (size_t)s * DMODEL + h * HDIM + lane;
    unsigned short hi = f2bf(o);
    ohi[oi] = hi;
    olo[oi] = f2bf(o - bf2f(hi));
}

// ---------------------------------------------------------------------------
// LayerNorm, one block per row of 1024
// ---------------------------------------------------------------------------
__global__ __launch_bounds__(256) void layernorm_k(
    const float* __restrict__ res, const float* __restrict__ gamma,
    const float* __restrict__ beta, float* __restrict__ y)
{
    const int row  = blockIdx.x;
    const int tid  = threadIdx.x;
    const int wave = tid >> 6;
    const int lane = tid & 63;
    const float* r = res + (size_t)row * DMODEL;

    float4 xv = *(const float4*)&r[tid * 4];
    float ssum = xv.x + xv.y + xv.z + xv.w;
    float ssq  = xv.x * xv.x + xv.y * xv.y + xv.z * xv.z + xv.w * xv.w;

    #pragma unroll
    for (int off = 1; off < 64; off <<= 1) {
        ssum += __shfl_xor(ssum, off);
        ssq  += __shfl_xor(ssq, off);
    }

    __shared__ float wsum[4], wsq[4];
    if (lane == 0) { wsum[wave] = ssum; wsq[wave] = ssq; }
    __syncthreads();

    float tot  = wsum[0] + wsum[1] + wsum[2] + wsum[3];
    float tot2 = wsq[0] + wsq[1] + wsq[2] + wsq[3];
    float mu   = tot * (1.0f / DMODEL);
    float var  = tot2 * (1.0f / DMODEL) - mu * mu;
    float rstd = rsqrtf(var + 1e-5f);

    float4 gm = *(const float4*)&gamma[tid * 4];
    float4 be = *(const float4*)&beta[tid * 4];
    float4 yo;
    yo.x = (xv.x - mu) * rstd * gm.x + be.x;
    yo.y = (xv.y - mu) * rstd * gm.y + be.y;
    yo.z = (xv.z - mu) * rstd * gm.z + be.z;
    yo.w = (xv.w - mu) * rstd * gm.w + be.w;
    *(float4*)&y[(size_t)row * DMODEL + tid * 4] = yo;
}

// ---------------------------------------------------------------------------
extern "C" void kernel_launch(void* const* d_in, const int* in_sizes, int n_in,
                              void* d_out, int out_size, void* d_ws, size_t ws_size,
                              hipStream_t stream) {
    const float* x     = (const float*)d_in[0];
    const float* state = (const float*)d_in[1];
    const float* Wqkv  = (const float*)d_in[2];
    const float* Wout  = (const float*)d_in[3];
    const float* gamma = (const float*)d_in[4];
    const float* beta  = (const float*)d_in[5];
    float* out = (float*)d_out;

    char* base = (char*)d_ws;
    // region A (25.2 MB): qkv_raw first, later reused for attn hi/lo + res
    float*          qkv_raw = (float*)base;                          // S*3072 f32
    unsigned short* ahi     = (unsigned short*)base;                 // S*1024 bf16
    unsigned short* alo     = (unsigned short*)(base + 4194304);     // S*1024 bf16
    float*          res     = (float*)(base + 8388608);              // S*1024 f32
    float* qb = (float*)(base + 25165824);                           // H*S*64
    float* kb = (float*)(base + 33554432);
    float* vb = (float*)(base + 41943040);
    unsigned short* WqkvT_h = (unsigned short*)(base + 50331648);    // [3072][1024]
    unsigned short* WqkvT_l = (unsigned short*)(base + 56623104);
    unsigned short* WoutT_h = (unsigned short*)(base + 62914560);    // [1024][1024]
    unsigned short* WoutT_l = (unsigned short*)(base + 65011712);
    unsigned short* xhi     = (unsigned short*)(base + 67108864);    // [2048][1024]
    unsigned short* xlo     = (unsigned short*)(base + 71303168);

    // --- prep: splits + weight transposes ---
    split_f32<<<(S_LEN * DMODEL) / 1024, 256, 0, stream>>>(x, xhi, xlo);
    transpose_split<<<dim3(N_QKV / 32, DMODEL / 32), 256, 0, stream>>>(
        Wqkv, WqkvT_h, WqkvT_l, DMODEL, N_QKV);
    transpose_split<<<dim3(DMODEL / 32, DMODEL / 32), 256, 0, stream>>>(
        Wout, WoutT_h, WoutT_l, DMODEL, DMODEL);

    // --- QKV projection: [2048,1024] x [1024,3072] ---
    gemm_bf16x3<128, 128, false>
        <<<dim3(N_QKV / 128, S_LEN / 128), 256, 0, stream>>>(
            xhi, xlo, WqkvT_h, WqkvT_l, nullptr, qkv_raw,
            S_LEN, N_QKV, DMODEL);

    // --- RoPE + scatter ---
    rope_scatter<<<(S_LEN * DMODEL) / 256, 256, 0, stream>>>(qkv_raw, qb, kb, vb);

    // --- windowed attention (writes hi/lo bf16 over dead qkv_raw region) ---
    attn_win<<<dim3(S_LEN / 16, NHEADS), 1024, 0, stream>>>(qb, kb, vb, ahi, alo);

    // --- out projection + residual: [2048,1024] x [1024,1024] + x ---
    gemm_bf16x3<128, 64, true>
        <<<dim3(DMODEL / 64, S_LEN / 128), 256, 0, stream>>>(
            ahi, alo, WoutT_h, WoutT_l, x, res,
            S_LEN, DMODEL, DMODEL);

    // --- LayerNorm ---
    layernorm_k<<<S_LEN, 256, 0, stream>>>(res, gamma, beta, out);

    // --- state passthrough ---
    hipMemcpyAsync(out + (size_t)S_LEN * DMODEL, state,
                   (size_t)DMODEL * sizeof(float),
                   hipMemcpyDeviceToDevice, stream);
}

// Round 4
// 226.250 us; speedup vs baseline: 2.4773x; 2.4773x over previous
//
#include <hip/hip_runtime.h>
#include <math.h>

#define S_LEN 2048
#define DMODEL 1024
#define NHEADS 16
#define HDIM 64
#define WIN 256
#define N_QKV 3072

typedef __attribute__((ext_vector_type(8))) short s16x8;
typedef __attribute__((ext_vector_type(4))) float f32x4;

__device__ inline unsigned short f2bf(float f) {
    unsigned int u = __float_as_uint(f);
    u += 0x7FFFu + ((u >> 16) & 1u);      // round-to-nearest-even
    return (unsigned short)(u >> 16);
}
__device__ inline float bf2f(unsigned short h) {
    return __uint_as_float(((unsigned int)h) << 16);
}

// ---------------------------------------------------------------------------
// split fp32 -> (hi, lo) bf16, elementwise.  4 floats / thread.
// ---------------------------------------------------------------------------
__global__ __launch_bounds__(256) void split_f32(
    const float* __restrict__ src, unsigned short* __restrict__ hi,
    unsigned short* __restrict__ lo)
{
    int i = blockIdx.x * 256 + threadIdx.x;
    float4 v = *(const float4*)&src[i * 4];
    ushort4 h, l;
    h.x = f2bf(v.x); l.x = f2bf(v.x - bf2f(h.x));
    h.y = f2bf(v.y); l.y = f2bf(v.y - bf2f(h.y));
    h.z = f2bf(v.z); l.z = f2bf(v.z - bf2f(h.z));
    h.w = f2bf(v.w); l.w = f2bf(v.w - bf2f(h.w));
    *(ushort4*)&hi[i * 4] = h;
    *(ushort4*)&lo[i * 4] = l;
}

// ---------------------------------------------------------------------------
// W [K][N] f32  ->  WT_hi / WT_lo [N][K] bf16   (32x32 tiles)
// ---------------------------------------------------------------------------
__global__ __launch_bounds__(256) void transpose_split(
    const float* __restrict__ W, unsigned short* __restrict__ Thi,
    unsigned short* __restrict__ Tlo, int K, int N)
{
    __shared__ float t[32][33];
    const int tx = threadIdx.x & 31;
    const int ty = threadIdx.x >> 5;          // 0..7
    const int n0 = blockIdx.x * 32, k0 = blockIdx.y * 32;

    #pragma unroll
    for (int i = 0; i < 4; ++i)
        t[ty + i * 8][tx] = W[(size_t)(k0 + ty + i * 8) * N + n0 + tx];
    __syncthreads();
    #pragma unroll
    for (int i = 0; i < 4; ++i) {
        int n = n0 + ty + i * 8;
        float v = t[tx][ty + i * 8];
        unsigned short h = f2bf(v);
        Thi[(size_t)n * K + k0 + tx] = h;
        Tlo[(size_t)n * K + k0 + tx] = f2bf(v - bf2f(h));
    }
}

// ---------------------------------------------------------------------------
// bf16x3 split-precision MFMA GEMM (validated round 2).
// C[M,N] = A[M,K] @ B[K,N] (+resid), A hi/lo bf16 [M][K], B hi/lo bf16 [N][K].
// ---------------------------------------------------------------------------
template<int BM, int BN, bool RES>
__global__ __launch_bounds__(256) void gemm_bf16x3(
    const unsigned short* __restrict__ Ahi, const unsigned short* __restrict__ Alo,
    const unsigned short* __restrict__ Bhi, const unsigned short* __restrict__ Blo,
    const float* __restrict__ resid, float* __restrict__ C,
    int M, int N, int K)
{
    constexpr int P  = 40;
    constexpr int MI = 4;
    constexpr int NJ = BN / 32;

    __shared__ unsigned short As_h[BM][P], As_l[BM][P];
    __shared__ unsigned short Bs_h[BN][P], Bs_l[BN][P];

    const int tid  = threadIdx.x;
    const int w    = tid >> 6;
    const int lane = tid & 63;
    const int m16  = lane & 15;
    const int g    = lane >> 4;
    const int wr   = w >> 1, wc = w & 1;
    const int bm   = blockIdx.y * BM, bn = blockIdx.x * BN;

    f32x4 acc[MI][NJ];
    #pragma unroll
    for (int i = 0; i < MI; ++i)
        #pragma unroll
        for (int j = 0; j < NJ; ++j) acc[i][j] = (f32x4)(0.0f);

    for (int k0 = 0; k0 < K; k0 += 32) {
        __syncthreads();
        for (int f = tid; f < BM * 4; f += 256) {
            int r = f >> 2, c = (f & 3) * 8;
            *(s16x8*)&As_h[r][c] = *(const s16x8*)&Ahi[(size_t)(bm + r) * K + k0 + c];
            *(s16x8*)&As_l[r][c] = *(const s16x8*)&Alo[(size_t)(bm + r) * K + k0 + c];
        }
        for (int f = tid; f < BN * 4; f += 256) {
            int r = f >> 2, c = (f & 3) * 8;
            *(s16x8*)&Bs_h[r][c] = *(const s16x8*)&Bhi[(size_t)(bn + r) * K + k0 + c];
            *(s16x8*)&Bs_l[r][c] = *(const s16x8*)&Blo[(size_t)(bn + r) * K + k0 + c];
        }
        __syncthreads();

        s16x8 ah[MI], al[MI];
        #pragma unroll
        for (int i = 0; i < MI; ++i) {
            ah[i] = *(const s16x8*)&As_h[wr * 64 + i * 16 + m16][g * 8];
            al[i] = *(const s16x8*)&As_l[wr * 64 + i * 16 + m16][g * 8];
        }
        #pragma unroll
        for (int j = 0; j < NJ; ++j) {
            s16x8 bh = *(const s16x8*)&Bs_h[wc * (BN / 2) + j * 16 + m16][g * 8];
            s16x8 bl = *(const s16x8*)&Bs_l[wc * (BN / 2) + j * 16 + m16][g * 8];
            #pragma unroll
            for (int i = 0; i < MI; ++i) {
                acc[i][j] = __builtin_amdgcn_mfma_f32_16x16x32_bf16(ah[i], bh, acc[i][j], 0, 0, 0);
                acc[i][j] = __builtin_amdgcn_mfma_f32_16x16x32_bf16(ah[i], bl, acc[i][j], 0, 0, 0);
                acc[i][j] = __builtin_amdgcn_mfma_f32_16x16x32_bf16(al[i], bh, acc[i][j], 0, 0, 0);
            }
        }
    }

    const int g4 = g * 4;
    #pragma unroll
    for (int i = 0; i < MI; ++i)
        #pragma unroll
        for (int j = 0; j < NJ; ++j) {
            int col = bn + wc * (BN / 2) + j * 16 + m16;
            #pragma unroll
            for (int r = 0; r < 4; ++r) {
                int row = bm + wr * 64 + i * 16 + g4 + r;
                float val = acc[i][j][r];
                if (RES) val += resid[(size_t)row * N + col];
                C[(size_t)row * N + col] = val;
            }
        }
}

// ---------------------------------------------------------------------------
// RoPE + scatter qkv[S,3072] -> q f32 [H][S][64], k hi/lo bf16 [H][S][64]
// ---------------------------------------------------------------------------
__global__ __launch_bounds__(256) void rope_scatter(
    const float* __restrict__ qkv, float* __restrict__ q,
    unsigned short* __restrict__ khi, unsigned short* __restrict__ klo)
{
    int idx = blockIdx.x * 256 + threadIdx.x;   // 0 .. S*D-1
    int s  = idx >> 10;
    int r  = idx & 1023;
    int hd = r & 63;
    int h  = r >> 6;
    const float* row = qkv + (size_t)s * N_QKV;

    float qv = row[r];
    float kv = row[DMODEL + r];

    int   i   = hd & 31;
    float inv = expf(-(float)i * 0.2878231366242553f);   // 10000^(-i/32)
    float ang = (float)s * inv;
    float c  = cosf(ang);
    float sn = sinf(ang);

    int   pr  = (hd < 32) ? r + 32 : r - 32;
    float sgn = (hd < 32) ? -1.0f : 1.0f;

    float qo = qv * c + sgn * row[pr] * sn;
    float ko = kv * c + sgn * row[DMODEL + pr] * sn;

    size_t o = ((size_t)h * S_LEN + s) * HDIM + hd;
    q[o] = qo;
    unsigned short kh = f2bf(ko);
    khi[o] = kh;
    klo[o] = f2bf(ko - bf2f(kh));
}

// ---------------------------------------------------------------------------
// V transpose: qkv_raw v-part [s][h*64+d] f32 -> vT [h][d][s] bf16
// ---------------------------------------------------------------------------
__global__ __launch_bounds__(256) void v_transpose(
    const float* __restrict__ qkv, unsigned short* __restrict__ vT)
{
    __shared__ float t[64][65];
    const int s0 = blockIdx.x * 64;
    const int h  = blockIdx.y;
    const int tid = threadIdx.x;
    const int dq  = (tid & 15) * 4;
    const int sl0 = tid >> 4;

    #pragma unroll
    for (int p = 0; p < 4; ++p) {
        int sl = sl0 + p * 16;
        float4 v = *(const float4*)&qkv[(size_t)(s0 + sl) * N_QKV + 2 * DMODEL + h * HDIM + dq];
        t[sl][dq] = v.x; t[sl][dq + 1] = v.y; t[sl][dq + 2] = v.z; t[sl][dq + 3] = v.w;
    }
    __syncthreads();
    #pragma unroll
    for (int p = 0; p < 2; ++p) {
        int u = tid + p * 256;
        int d = u >> 3, sb = (u & 7) * 8;
        s16x8 o;
        #pragma unroll
        for (int i = 0; i < 8; ++i) o[i] = (short)f2bf(t[sb + i][d]);
        *(s16x8*)&vT[((size_t)h * HDIM + d) * S_LEN + s0 + sb] = o;
    }
}

// ---------------------------------------------------------------------------
// MFMA flash-style windowed attention.
// Block: (head, 64-query tile), 4 waves x 16 queries.  Keys staged 64/iter.
// Scores = mfma(A=K, B=Q) -> D[key][query]; K hi/lo split (fp32-grade),
// P,V plain bf16.  Output written as hi/lo bf16 split for GEMM2.
// ---------------------------------------------------------------------------
#define KP 72   // LDS pitch (bf16): 144 B rows -> <=2-way bank aliasing
__global__ __launch_bounds__(256, 3) void attn_mfma(
    const float* __restrict__ qg, const unsigned short* __restrict__ khg,
    const unsigned short* __restrict__ klg, const unsigned short* __restrict__ vTg,
    unsigned short* __restrict__ ohi, unsigned short* __restrict__ olo)
{
    __shared__ __align__(16) unsigned short Kh[64][KP], Kl[64][KP], Vt[64][KP];
    __shared__ __align__(16) unsigned short Pw[4][16][40];

    const int h   = blockIdx.y;
    const int s0  = blockIdx.x * 64;
    const int tid = threadIdx.x;
    const int w   = tid >> 6, lane = tid & 63;
    const int m16 = lane & 15, g = lane >> 4;
    const int t_base = s0 - 256;

    // ---- Q fragments: scale 1/8, hi/lo split, direct from global ----
    const int qrow = s0 + w * 16 + m16;
    const float* qp = qg + ((size_t)h * S_LEN + qrow) * HDIM;
    s16x8 qh[2], ql[2];
    #pragma unroll
    for (int c = 0; c < 2; ++c) {
        float4 f0 = *(const float4*)&qp[c * 32 + g * 8];
        float4 f1 = *(const float4*)&qp[c * 32 + g * 8 + 4];
        float f[8] = {f0.x, f0.y, f0.z, f0.w, f1.x, f1.y, f1.z, f1.w};
        #pragma unroll
        for (int j = 0; j < 8; ++j) {
            float v = f[j] * 0.125f;
            unsigned short hb = f2bf(v);
            qh[c][j] = (short)hb;
            ql[c][j] = (short)f2bf(v - bf2f(hb));
        }
    }

    // valid key range (block-local ki in 0..319) for this lane's score COLUMN
    const int qb = w * 16 + m16;
    int lo_b = 256 - s0; if (lo_b < qb) lo_b = qb;
    const int hi_b = qb + 256;

    f32x4 O[4];
    #pragma unroll
    for (int nt = 0; nt < 4; ++nt) O[nt] = (f32x4)(0.0f);
    float l_r[4] = {0.0f, 0.0f, 0.0f, 0.0f};
    float m_col = -1e30f;

    const int stage_min = (s0 >= 256) ? 0 : ((193 - s0 + 63) >> 6);

    for (int st = stage_min; st < 5; ++st) {
        __syncthreads();
        // ---- stage 64 keys: K hi/lo row-major, V transposed (dims x keys) ----
        const int t0s = t_base + st * 64;
        #pragma unroll
        for (int pp = 0; pp < 2; ++pp) {
            int u = tid + pp * 256;
            int row = u >> 3, cb = (u & 7) * 8;
            int t = t0s + row;
            s16x8 vh = {}, vl = {};
            if (t >= 0) {
                size_t base = ((size_t)h * S_LEN + t) * HDIM + cb;
                vh = *(const s16x8*)&khg[base];
                vl = *(const s16x8*)&klg[base];
            }
            *(s16x8*)&Kh[row][cb] = vh;
            *(s16x8*)&Kl[row][cb] = vl;
        }
        #pragma unroll
        for (int pp = 0; pp < 2; ++pp) {
            int u = tid + pp * 256;
            int d = u >> 3, kb = (u & 7) * 8;
            int t = t0s + kb;
            s16x8 vv = {};
            if (t >= 0)
                vv = *(const s16x8*)&vTg[((size_t)h * HDIM + d) * S_LEN + t];
            *(s16x8*)&Vt[d][kb] = vv;
        }
        __syncthreads();

        #pragma unroll
        for (int ch = 0; ch < 2; ++ch) {
            // ---- scores: 2 sub-tiles of 16 keys, K=64 dims, bf16x3 split ----
            f32x4 sc[2];
            #pragma unroll
            for (int kt2 = 0; kt2 < 2; ++kt2) {
                int krow = ch * 32 + kt2 * 16 + m16;
                s16x8 kh0 = *(const s16x8*)&Kh[krow][g * 8];
                s16x8 kh1 = *(const s16x8*)&Kh[krow][32 + g * 8];
                s16x8 kl0 = *(const s16x8*)&Kl[krow][g * 8];
                s16x8 kl1 = *(const s16x8*)&Kl[krow][32 + g * 8];
                f32x4 a = (f32x4)(0.0f);
                a = __builtin_amdgcn_mfma_f32_16x16x32_bf16(kh0, qh[0], a, 0, 0, 0);
                a = __builtin_amdgcn_mfma_f32_16x16x32_bf16(kh1, qh[1], a, 0, 0, 0);
                a = __builtin_amdgcn_mfma_f32_16x16x32_bf16(kh0, ql[0], a, 0, 0, 0);
                a = __builtin_amdgcn_mfma_f32_16x16x32_bf16(kh1, ql[1], a, 0, 0, 0);
                a = __builtin_amdgcn_mfma_f32_16x16x32_bf16(kl0, qh[0], a, 0, 0, 0);
                a = __builtin_amdgcn_mfma_f32_16x16x32_bf16(kl1, qh[1], a, 0, 0, 0);
                sc[kt2] = a;
            }

            // ---- mask + online softmax (col stats -> row updates) ----
            float scm[8];
            float pmax = -1e30f;
            #pragma unroll
            for (int kt2 = 0; kt2 < 2; ++kt2)
                #pragma unroll
                for (int r = 0; r < 4; ++r) {
                    int ki = st * 64 + ch * 32 + kt2 * 16 + 4 * g + r;
                    bool vd = (ki >= lo_b) && (ki <= hi_b);
                    float s_ = vd ? sc[kt2][r] : -1e30f;
                    scm[kt2 * 4 + r] = s_;
                    pmax = fmaxf(pmax, s_);
                }
            pmax = fmaxf(pmax, __shfl_xor(pmax, 16));
            pmax = fmaxf(pmax, __shfl_xor(pmax, 32));
            float mnew = fmaxf(m_col, pmax);

            float p[8];
            float psum = 0.0f;
            #pragma unroll
            for (int i = 0; i < 8; ++i) {
                float e = (scm[i] > -9e29f) ? __expf(scm[i] - mnew) : 0.0f;
                p[i] = e;
                psum += e;
            }
            psum += __shfl_xor(psum, 16);
            psum += __shfl_xor(psum, 32);
            float scale = __expf(m_col - mnew);
            m_col = mnew;

            #pragma unroll
            for (int r = 0; r < 4; ++r) {
                float sr = __shfl(scale, 4 * g + r);
                float ps = __shfl(psum, 4 * g + r);
                l_r[r] = l_r[r] * sr + ps;
                O[0][r] *= sr; O[1][r] *= sr; O[2][r] *= sr; O[3][r] *= sr;
            }

            // ---- P -> bf16 -> per-wave LDS -> A-fragment ----
            unsigned int d0, d1, d2, d3;
            asm("v_cvt_pk_bf16_f32 %0, %1, %2" : "=v"(d0) : "v"(p[0]), "v"(p[1]));
            asm("v_cvt_pk_bf16_f32 %0, %1, %2" : "=v"(d1) : "v"(p[2]), "v"(p[3]));
            asm("v_cvt_pk_bf16_f32 %0, %1, %2" : "=v"(d2) : "v"(p[4]), "v"(p[5]));
            asm("v_cvt_pk_bf16_f32 %0, %1, %2" : "=v"(d3) : "v"(p[6]), "v"(p[7]));
            *(uint2*)&Pw[w][m16][4 * g]      = make_uint2(d0, d1);
            *(uint2*)&Pw[w][m16][16 + 4 * g] = make_uint2(d2, d3);
            asm volatile("s_waitcnt lgkmcnt(0)" ::: "memory");
            __builtin_amdgcn_sched_barrier(0);
            s16x8 pa = *(const s16x8*)&Pw[w][m16][g * 8];

            // ---- PV: O += P[16x32] . V[32x64] ----
            #pragma unroll
            for (int nt = 0; nt < 4; ++nt) {
                s16x8 vb = *(const s16x8*)&Vt[nt * 16 + m16][ch * 32 + g * 8];
                O[nt] = __builtin_amdgcn_mfma_f32_16x16x32_bf16(pa, vb, O[nt], 0, 0, 0);
            }
        }
    }

    // ---- epilogue: normalize, hi/lo split, scatter to [s][h*64+d] ----
    #pragma unroll
    for (int r = 0; r < 4; ++r) {
        float linv = 1.0f / l_r[r];
        int srow = s0 + w * 16 + 4 * g + r;
        size_t obase = (size_t)srow * DMODEL + h * HDIM;
        #pragma unroll
        for (int nt = 0; nt < 4; ++nt) {
            float val = O[nt][r] * linv;
            unsigned short hb = f2bf(val);
            ohi[obase + nt * 16 + m16] = hb;
            olo[obase + nt * 16 + m16] = f2bf(val - bf2f(hb));
        }
    }
}

// ---------------------------------------------------------------------------
// LayerNorm, one block per row of 1024
// ---------------------------------------------------------------------------
__global__ __launch_bounds__(256) void layernorm_k(
    const float* __restrict__ res, const float* __restrict__ gamma,
    const float* __restrict__ beta, float* __restrict__ y)
{
    const int row  = blockIdx.x;
    const int tid  = threadIdx.x;
    const int wave = tid >> 6;
    const int lane = tid & 63;
    const float* r = res + (size_t)row * DMODEL;

    float4 xv = *(const float4*)&r[tid * 4];
    float ssum = xv.x + xv.y + xv.z + xv.w;
    float ssq  = xv.x * xv.x + xv.y * xv.y + xv.z * xv.z + xv.w * xv.w;

    #pragma unroll
    for (int off = 1; off < 64; off <<= 1) {
        ssum += __shfl_xor(ssum, off);
        ssq  += __shfl_xor(ssq, off);
    }

    __shared__ float wsum[4], wsq[4];
    if (lane == 0) { wsum[wave] = ssum; wsq[wave] = ssq; }
    __syncthreads();

    float tot  = wsum[0] + wsum[1] + wsum[2] + wsum[3];
    float tot2 = wsq[0] + wsq[1] + wsq[2] + wsq[3];
    float mu   = tot * (1.0f / DMODEL);
    float var  = tot2 * (1.0f / DMODEL) - mu * mu;
    float rstd = rsqrtf(var + 1e-5f);

    float4 gm = *(const float4*)&gamma[tid * 4];
    float4 be = *(const float4*)&beta[tid * 4];
    float4 yo;
    yo.x = (xv.x - mu) * rstd * gm.x + be.x;
    yo.y = (xv.y - mu) * rstd * gm.y + be.y;
    yo.z = (xv.z - mu) * rstd * gm.z + be.z;
    yo.w = (xv.w - mu) * rstd * gm.w + be.w;
    *(float4*)&y[(size_t)row * DMODEL + tid * 4] = yo;
}

// ---------------------------------------------------------------------------
extern "C" void kernel_launch(void* const* d_in, const int* in_sizes, int n_in,
                              void* d_out, int out_size, void* d_ws, size_t ws_size,
                              hipStream_t stream) {
    const float* x     = (const float*)d_in[0];
    const float* state = (const float*)d_in[1];
    const float* Wqkv  = (const float*)d_in[2];
    const float* Wout  = (const float*)d_in[3];
    const float* gamma = (const float*)d_in[4];
    const float* beta  = (const float*)d_in[5];
    float* out = (float*)d_out;

    char* base = (char*)d_ws;
    // region A (25.2 MB): qkv_raw first, later reused for attn hi/lo + res
    float*          qkv_raw = (float*)base;                          // S*3072 f32
    unsigned short* ahi     = (unsigned short*)base;                 // S*1024 bf16
    unsigned short* alo     = (unsigned short*)(base + 4194304);
    float*          res     = (float*)(base + 8388608);              // S*1024 f32
    float*          qb      = (float*)(base + 25165824);             // H*S*64 f32
    unsigned short* khi     = (unsigned short*)(base + 33554432);    // H*S*64 bf16
    unsigned short* klo     = (unsigned short*)(base + 37748736);
    unsigned short* vT      = (unsigned short*)(base + 41943040);    // H*64*S bf16
    unsigned short* WqkvT_h = (unsigned short*)(base + 46137344);    // [3072][1024]
    unsigned short* WqkvT_l = (unsigned short*)(base + 52428800);
    unsigned short* WoutT_h = (unsigned short*)(base + 58720256);    // [1024][1024]
    unsigned short* WoutT_l = (unsigned short*)(base + 60817408);
    unsigned short* xhi     = (unsigned short*)(base + 62914560);    // [2048][1024]
    unsigned short* xlo     = (unsigned short*)(base + 67108864);

    // --- prep: splits + weight transposes ---
    split_f32<<<(S_LEN * DMODEL) / 1024, 256, 0, stream>>>(x, xhi, xlo);
    transpose_split<<<dim3(N_QKV / 32, DMODEL / 32), 256, 0, stream>>>(
        Wqkv, WqkvT_h, WqkvT_l, DMODEL, N_QKV);
    transpose_split<<<dim3(DMODEL / 32, DMODEL / 32), 256, 0, stream>>>(
        Wout, WoutT_h, WoutT_l, DMODEL, DMODEL);

    // --- QKV projection: [2048,1024] x [1024,3072] ---
    gemm_bf16x3<128, 128, false>
        <<<dim3(N_QKV / 128, S_LEN / 128), 256, 0, stream>>>(
            xhi, xlo, WqkvT_h, WqkvT_l, nullptr, qkv_raw,
            S_LEN, N_QKV, DMODEL);

    // --- RoPE + scatter (q f32, k hi/lo bf16) ---
    rope_scatter<<<(S_LEN * DMODEL) / 256, 256, 0, stream>>>(qkv_raw, qb, khi, klo);

    // --- V transpose to [h][d][s] bf16 ---
    v_transpose<<<dim3(S_LEN / 64, NHEADS), 256, 0, stream>>>(qkv_raw, vT);

    // --- MFMA windowed attention (writes hi/lo bf16 over dead qkv_raw) ---
    attn_mfma<<<dim3(S_LEN / 64, NHEADS), 256, 0, stream>>>(
        qb, khi, klo, vT, ahi, alo);

    // --- out projection + residual: [2048,1024] x [1024,1024] + x ---
    gemm_bf16x3<128, 64, true>
        <<<dim3(DMODEL / 64, S_LEN / 128), 256, 0, stream>>>(
            ahi, alo, WoutT_h, WoutT_l, x, res,
            S_LEN, DMODEL, DMODEL);

    // --- LayerNorm ---
    layernorm_k<<<S_LEN, 256, 0, stream>>>(res, gamma, beta, out);

    // --- state passthrough ---
    hipMemcpyAsync(out + (size_t)S_LEN * DMODEL, state,
                   (size_t)DMODEL * sizeof(float),
                   hipMemcpyDeviceToDevice, stream);
}

// Round 6
// 185.140 us; speedup vs baseline: 3.0274x; 1.2220x over previous
//
#include <hip/hip_runtime.h>
#include <math.h>

#define S_LEN 2048
#define DMODEL 1024
#define NHEADS 16
#define HDIM 64
#define WIN 256
#define N_QKV 3072

typedef __attribute__((ext_vector_type(8))) short s16x8;
typedef __attribute__((ext_vector_type(8))) _Float16 f16x8;
typedef __attribute__((ext_vector_type(4))) _Float16 f16x4;
typedef __attribute__((ext_vector_type(4))) float f32x4;

__device__ inline unsigned short f2bf(float f) {
    unsigned int u = __float_as_uint(f);
    u += 0x7FFFu + ((u >> 16) & 1u);      // round-to-nearest-even
    return (unsigned short)(u >> 16);
}
__device__ inline float bf2f(unsigned short h) {
    return __uint_as_float(((unsigned int)h) << 16);
}

// ---------------------------------------------------------------------------
// fp32 -> fp16 convert, 4 elems/thread
// ---------------------------------------------------------------------------
__global__ __launch_bounds__(256) void cvt_f16(
    const float* __restrict__ src, _Float16* __restrict__ dst)
{
    int i = blockIdx.x * 256 + threadIdx.x;
    float4 v = *(const float4*)&src[i * 4];
    f16x4 o;
    o[0] = (_Float16)v.x; o[1] = (_Float16)v.y;
    o[2] = (_Float16)v.z; o[3] = (_Float16)v.w;
    *(f16x4*)&dst[i * 4] = o;
}

// ---------------------------------------------------------------------------
// W [K][N] f32 -> WT [N][K] fp16  (32x32 tiles)
// ---------------------------------------------------------------------------
__global__ __launch_bounds__(256) void transpose_cvt(
    const float* __restrict__ W, _Float16* __restrict__ T, int K, int N)
{
    __shared__ float t[32][33];
    const int tx = threadIdx.x & 31;
    const int ty = threadIdx.x >> 5;          // 0..7
    const int n0 = blockIdx.x * 32, k0 = blockIdx.y * 32;

    #pragma unroll
    for (int i = 0; i < 4; ++i)
        t[ty + i * 8][tx] = W[(size_t)(k0 + ty + i * 8) * N + n0 + tx];
    __syncthreads();
    #pragma unroll
    for (int i = 0; i < 4; ++i) {
        int n = n0 + ty + i * 8;
        T[(size_t)n * K + k0 + tx] = (_Float16)t[tx][ty + i * 8];
    }
}

// ---------------------------------------------------------------------------
// fp16 single-pass MFMA GEMM.  C[M,N] = A[M,K] @ B[K,N] (+resid)
// A fp16 [M][K] row-major, B fp16 of B^T: [N][K] row-major.
// Tiles: BM x BN, BK=32, 4 waves as 2x2 (wave tile WM x WN).
// LDS rows are exactly 64 B (32 f16) with XOR swizzle cb^=(row>>1)&3:
// staging writes and fragment reads are both 16B-granule permutations
// (<=2 lanes per bank slot per quarter-wave = conflict-free).
// Reg-staged write-late double buffer: next tile's global loads issue
// before the MFMA block, overlapping L2 latency with compute.
// ---------------------------------------------------------------------------
template<int BM, int BN, int WM, int WN, bool RES>
__global__ __launch_bounds__(256) void gemm_f16(
    const _Float16* __restrict__ A, const _Float16* __restrict__ B,
    const float* __restrict__ resid, float* __restrict__ C,
    int M, int N, int K)
{
    constexpr int MI = WM / 16;
    constexpr int NJ = WN / 16;
    constexpr int APASS = BM / 64;
    constexpr int BPASS = BN / 64;
    static_assert(WM * 2 == BM && WN * 2 == BN, "4 waves as 2x2");

    __shared__ _Float16 As[BM * 32];
    __shared__ _Float16 Bs[BN * 32];

    const int tid  = threadIdx.x;
    const int w    = tid >> 6;
    const int lane = tid & 63;
    const int m16  = lane & 15;
    const int g    = lane >> 4;
    const int wr   = w >> 1, wc = w & 1;
    const int bm   = blockIdx.y * BM, bn = blockIdx.x * BN;

    f32x4 acc[MI][NJ];
    #pragma unroll
    for (int i = 0; i < MI; ++i)
        #pragma unroll
        for (int j = 0; j < NJ; ++j) acc[i][j] = (f32x4)(0.0f);

    uint4 ra[APASS], rb[BPASS];

    // prologue load (k0 = 0)
    #pragma unroll
    for (int p = 0; p < APASS; ++p) {
        int f = p * 256 + tid, row = f >> 2, cb = f & 3;
        ra[p] = *(const uint4*)&A[(size_t)(bm + row) * K + cb * 8];
    }
    #pragma unroll
    for (int p = 0; p < BPASS; ++p) {
        int f = p * 256 + tid, row = f >> 2, cb = f & 3;
        rb[p] = *(const uint4*)&B[(size_t)(bn + row) * K + cb * 8];
    }

    const int NT = K / 32;
    for (int kt = 0; kt < NT; ++kt) {
        __syncthreads();
        // regs -> LDS (swizzled)
        #pragma unroll
        for (int p = 0; p < APASS; ++p) {
            int f = p * 256 + tid, row = f >> 2, cb = f & 3;
            *(uint4*)&As[row * 32 + ((cb ^ ((row >> 1) & 3)) << 3)] = ra[p];
        }
        #pragma unroll
        for (int p = 0; p < BPASS; ++p) {
            int f = p * 256 + tid, row = f >> 2, cb = f & 3;
            *(uint4*)&Bs[row * 32 + ((cb ^ ((row >> 1) & 3)) << 3)] = rb[p];
        }
        __syncthreads();

        // issue next tile's global loads (in flight during MFMA)
        if (kt + 1 < NT) {
            int k0 = (kt + 1) * 32;
            #pragma unroll
            for (int p = 0; p < APASS; ++p) {
                int f = p * 256 + tid, row = f >> 2, cb = f & 3;
                ra[p] = *(const uint4*)&A[(size_t)(bm + row) * K + k0 + cb * 8];
            }
            #pragma unroll
            for (int p = 0; p < BPASS; ++p) {
                int f = p * 256 + tid, row = f >> 2, cb = f & 3;
                rb[p] = *(const uint4*)&B[(size_t)(bn + row) * K + k0 + cb * 8];
            }
        }

        // fragments + MFMA
        f16x8 af[MI], bf_[NJ];
        #pragma unroll
        for (int i = 0; i < MI; ++i) {
            int row = wr * WM + i * 16 + m16;
            af[i] = *(const f16x8*)&As[row * 32 + ((g ^ ((row >> 1) & 3)) << 3)];
        }
        #pragma unroll
        for (int j = 0; j < NJ; ++j) {
            int row = wc * WN + j * 16 + m16;
            bf_[j] = *(const f16x8*)&Bs[row * 32 + ((g ^ ((row >> 1) & 3)) << 3)];
        }
        #pragma unroll
        for (int j = 0; j < NJ; ++j)
            #pragma unroll
            for (int i = 0; i < MI; ++i)
                acc[i][j] = __builtin_amdgcn_mfma_f32_16x16x32_f16(
                    af[i], bf_[j], acc[i][j], 0, 0, 0);
    }

    // epilogue: C/D map col = lane&15, row = 4*(lane>>4)+reg  (HW-verified)
    const int g4 = g * 4;
    #pragma unroll
    for (int i = 0; i < MI; ++i)
        #pragma unroll
        for (int j = 0; j < NJ; ++j) {
            int col = bn + wc * WN + j * 16 + m16;
            #pragma unroll
            for (int r = 0; r < 4; ++r) {
                int row = bm + wr * WM + i * 16 + g4 + r;
                float val = acc[i][j][r];
                if (RES) val += resid[(size_t)row * N + col];
                C[(size_t)row * N + col] = val;
            }
        }
}

// ---------------------------------------------------------------------------
// RoPE + scatter qkv[S,3072] -> q f32 [H][S][64], k hi/lo bf16 [H][S][64]
// ---------------------------------------------------------------------------
__global__ __launch_bounds__(256) void rope_scatter(
    const float* __restrict__ qkv, float* __restrict__ q,
    unsigned short* __restrict__ khi, unsigned short* __restrict__ klo)
{
    int idx = blockIdx.x * 256 + threadIdx.x;   // 0 .. S*D-1
    int s  = idx >> 10;
    int r  = idx & 1023;
    int hd = r & 63;
    int h  = r >> 6;
    const float* row = qkv + (size_t)s * N_QKV;

    float qv = row[r];
    float kv = row[DMODEL + r];

    int   i   = hd & 31;
    float inv = expf(-(float)i * 0.2878231366242553f);   // 10000^(-i/32)
    float ang = (float)s * inv;
    float c  = cosf(ang);
    float sn = sinf(ang);

    int   pr  = (hd < 32) ? r + 32 : r - 32;
    float sgn = (hd < 32) ? -1.0f : 1.0f;

    float qo = qv * c + sgn * row[pr] * sn;
    float ko = kv * c + sgn * row[DMODEL + pr] * sn;

    size_t o = ((size_t)h * S_LEN + s) * HDIM + hd;
    q[o] = qo;
    unsigned short kh = f2bf(ko);
    khi[o] = kh;
    klo[o] = f2bf(ko - bf2f(kh));
}

// ---------------------------------------------------------------------------
// V transpose: qkv_raw v-part [s][h*64+d] f32 -> vT [h][d][s] bf16
// ---------------------------------------------------------------------------
__global__ __launch_bounds__(256) void v_transpose(
    const float* __restrict__ qkv, unsigned short* __restrict__ vT)
{
    __shared__ float t[64][65];
    const int s0 = blockIdx.x * 64;
    const int h  = blockIdx.y;
    const int tid = threadIdx.x;
    const int dq  = (tid & 15) * 4;
    const int sl0 = tid >> 4;

    #pragma unroll
    for (int p = 0; p < 4; ++p) {
        int sl = sl0 + p * 16;
        float4 v = *(const float4*)&qkv[(size_t)(s0 + sl) * N_QKV + 2 * DMODEL + h * HDIM + dq];
        t[sl][dq] = v.x; t[sl][dq + 1] = v.y; t[sl][dq + 2] = v.z; t[sl][dq + 3] = v.w;
    }
    __syncthreads();
    #pragma unroll
    for (int p = 0; p < 2; ++p) {
        int u = tid + p * 256;
        int d = u >> 3, sb = (u & 7) * 8;
        s16x8 o;
        #pragma unroll
        for (int i = 0; i < 8; ++i) o[i] = (short)f2bf(t[sb + i][d]);
        *(s16x8*)&vT[((size_t)h * HDIM + d) * S_LEN + s0 + sb] = o;
    }
}

// ---------------------------------------------------------------------------
// MFMA flash-style windowed attention (validated round 4).
// Output written as fp16 (A-operand of GEMM2).
// ---------------------------------------------------------------------------
#define KP 72   // LDS pitch (bf16): 144 B rows -> <=2-way bank aliasing
__global__ __launch_bounds__(256, 3) void attn_mfma(
    const float* __restrict__ qg, const unsigned short* __restrict__ khg,
    const unsigned short* __restrict__ klg, const unsigned short* __restrict__ vTg,
    _Float16* __restrict__ oh)
{
    __shared__ __align__(16) unsigned short Kh[64][KP], Kl[64][KP], Vt[64][KP];
    __shared__ __align__(16) unsigned short Pw[4][16][40];

    const int h   = blockIdx.y;
    const int s0  = blockIdx.x * 64;
    const int tid = threadIdx.x;
    const int w   = tid >> 6, lane = tid & 63;
    const int m16 = lane & 15, g = lane >> 4;
    const int t_base = s0 - 256;

    // ---- Q fragments: scale 1/8, hi/lo split, direct from global ----
    const int qrow = s0 + w * 16 + m16;
    const float* qp = qg + ((size_t)h * S_LEN + qrow) * HDIM;
    s16x8 qh[2], ql[2];
    #pragma unroll
    for (int c = 0; c < 2; ++c) {
        float4 f0 = *(const float4*)&qp[c * 32 + g * 8];
        float4 f1 = *(const float4*)&qp[c * 32 + g * 8 + 4];
        float f[8] = {f0.x, f0.y, f0.z, f0.w, f1.x, f1.y, f1.z, f1.w};
        #pragma unroll
        for (int j = 0; j < 8; ++j) {
            float v = f[j] * 0.125f;
            unsigned short hb = f2bf(v);
            qh[c][j] = (short)hb;
            ql[c][j] = (short)f2bf(v - bf2f(hb));
        }
    }

    // valid key range (block-local ki in 0..319) for this lane's score COLUMN
    const int qb = w * 16 + m16;
    int lo_b = 256 - s0; if (lo_b < qb) lo_b = qb;
    const int hi_b = qb + 256;

    f32x4 O[4];
    #pragma unroll
    for (int nt = 0; nt < 4; ++nt) O[nt] = (f32x4)(0.0f);
    float l_r[4] = {0.0f, 0.0f, 0.0f, 0.0f};
    float m_col = -1e30f;

    const int stage_min = (s0 >= 256) ? 0 : ((193 - s0 + 63) >> 6);

    for (int st = stage_min; st < 5; ++st) {
        __syncthreads();
        // ---- stage 64 keys: K hi/lo row-major, V transposed (dims x keys) ----
        const int t0s = t_base + st * 64;
        #pragma unroll
        for (int pp = 0; pp < 2; ++pp) {
            int u = tid + pp * 256;
            int row = u >> 3, cb = (u & 7) * 8;
            int t = t0s + row;
            s16x8 vh = {}, vl = {};
            if (t >= 0) {
                size_t base = ((size_t)h * S_LEN + t) * HDIM + cb;
                vh = *(const s16x8*)&khg[base];
                vl = *(const s16x8*)&klg[base];
            }
            *(s16x8*)&Kh[row][cb] = vh;
            *(s16x8*)&Kl[row][cb] = vl;
        }
        #pragma unroll
        for (int pp = 0; pp < 2; ++pp) {
            int u = tid + pp * 256;
            int d = u >> 3, kb = (u & 7) * 8;
            int t = t0s + kb;
            s16x8 vv = {};
            if (t >= 0)
                vv = *(const s16x8*)&vTg[((size_t)h * HDIM + d) * S_LEN + t];
            *(s16x8*)&Vt[d][kb] = vv;
        }
        __syncthreads();

        #pragma unroll
        for (int ch = 0; ch < 2; ++ch) {
            // ---- scores: 2 sub-tiles of 16 keys, K=64 dims, bf16x3 split ----
            f32x4 sc[2];
            #pragma unroll
            for (int kt2 = 0; kt2 < 2; ++kt2) {
                int krow = ch * 32 + kt2 * 16 + m16;
                s16x8 kh0 = *(const s16x8*)&Kh[krow][g * 8];
                s16x8 kh1 = *(const s16x8*)&Kh[krow][32 + g * 8];
                s16x8 kl0 = *(const s16x8*)&Kl[krow][g * 8];
                s16x8 kl1 = *(const s16x8*)&Kl[krow][32 + g * 8];
                f32x4 a = (f32x4)(0.0f);
                a = __builtin_amdgcn_mfma_f32_16x16x32_bf16(kh0, qh[0], a, 0, 0, 0);
                a = __builtin_amdgcn_mfma_f32_16x16x32_bf16(kh1, qh[1], a, 0, 0, 0);
                a = __builtin_amdgcn_mfma_f32_16x16x32_bf16(kh0, ql[0], a, 0, 0, 0);
                a = __builtin_amdgcn_mfma_f32_16x16x32_bf16(kh1, ql[1], a, 0, 0, 0);
                a = __builtin_amdgcn_mfma_f32_16x16x32_bf16(kl0, qh[0], a, 0, 0, 0);
                a = __builtin_amdgcn_mfma_f32_16x16x32_bf16(kl1, qh[1], a, 0, 0, 0);
                sc[kt2] = a;
            }

            // ---- mask + online softmax (col stats -> row updates) ----
            float scm[8];
            float pmax = -1e30f;
            #pragma unroll
            for (int kt2 = 0; kt2 < 2; ++kt2)
                #pragma unroll
                for (int r = 0; r < 4; ++r) {
                    int ki = st * 64 + ch * 32 + kt2 * 16 + 4 * g + r;
                    bool vd = (ki >= lo_b) && (ki <= hi_b);
                    float s_ = vd ? sc[kt2][r] : -1e30f;
                    scm[kt2 * 4 + r] = s_;
                    pmax = fmaxf(pmax, s_);
                }
            pmax = fmaxf(pmax, __shfl_xor(pmax, 16));
            pmax = fmaxf(pmax, __shfl_xor(pmax, 32));
            float mnew = fmaxf(m_col, pmax);

            float p[8];
            float psum = 0.0f;
            #pragma unroll
            for (int i = 0; i < 8; ++i) {
                float e = (scm[i] > -9e29f) ? __expf(scm[i] - mnew) : 0.0f;
                p[i] = e;
                psum += e;
            }
            psum += __shfl_xor(psum, 16);
            psum += __shfl_xor(psum, 32);
            float scale = __expf(m_col - mnew);
            m_col = mnew;

            #pragma unroll
            for (int r = 0; r < 4; ++r) {
                float sr = __shfl(scale, 4 * g + r);
                float ps = __shfl(psum, 4 * g + r);
                l_r[r] = l_r[r] * sr + ps;
                O[0][r] *= sr; O[1][r] *= sr; O[2][r] *= sr; O[3][r] *= sr;
            }

            // ---- P -> bf16 -> per-wave LDS -> A-fragment ----
            unsigned int d0, d1, d2, d3;
            asm("v_cvt_pk_bf16_f32 %0, %1, %2" : "=v"(d0) : "v"(p[0]), "v"(p[1]));
            asm("v_cvt_pk_bf16_f32 %0, %1, %2" : "=v"(d1) : "v"(p[2]), "v"(p[3]));
            asm("v_cvt_pk_bf16_f32 %0, %1, %2" : "=v"(d2) : "v"(p[4]), "v"(p[5]));
            asm("v_cvt_pk_bf16_f32 %0, %1, %2" : "=v"(d3) : "v"(p[6]), "v"(p[7]));
            *(uint2*)&Pw[w][m16][4 * g]      = make_uint2(d0, d1);
            *(uint2*)&Pw[w][m16][16 + 4 * g] = make_uint2(d2, d3);
            asm volatile("s_waitcnt lgkmcnt(0)" ::: "memory");
            __builtin_amdgcn_sched_barrier(0);
            s16x8 pa = *(const s16x8*)&Pw[w][m16][g * 8];

            // ---- PV: O += P[16x32] . V[32x64] ----
            #pragma unroll
            for (int nt = 0; nt < 4; ++nt) {
                s16x8 vb = *(const s16x8*)&Vt[nt * 16 + m16][ch * 32 + g * 8];
                O[nt] = __builtin_amdgcn_mfma_f32_16x16x32_bf16(pa, vb, O[nt], 0, 0, 0);
            }
        }
    }

    // ---- epilogue: normalize, fp16, scatter to [s][h*64+d] ----
    #pragma unroll
    for (int r = 0; r < 4; ++r) {
        float linv = 1.0f / l_r[r];
        int srow = s0 + w * 16 + 4 * g + r;
        size_t obase = (size_t)srow * DMODEL + h * HDIM;
        #pragma unroll
        for (int nt = 0; nt < 4; ++nt)
            oh[obase + nt * 16 + m16] = (_Float16)(O[nt][r] * linv);
    }
}

// ---------------------------------------------------------------------------
// LayerNorm, one block per row of 1024
// ---------------------------------------------------------------------------
__global__ __launch_bounds__(256) void layernorm_k(
    const float* __restrict__ res, const float* __restrict__ gamma,
    const float* __restrict__ beta, float* __restrict__ y)
{
    const int row  = blockIdx.x;
    const int tid  = threadIdx.x;
    const int wave = tid >> 6;
    const int lane = tid & 63;
    const float* r = res + (size_t)row * DMODEL;

    float4 xv = *(const float4*)&r[tid * 4];
    float ssum = xv.x + xv.y + xv.z + xv.w;
    float ssq  = xv.x * xv.x + xv.y * xv.y + xv.z * xv.z + xv.w * xv.w;

    #pragma unroll
    for (int off = 1; off < 64; off <<= 1) {
        ssum += __shfl_xor(ssum, off);
        ssq  += __shfl_xor(ssq, off);
    }

    __shared__ float wsum[4], wsq[4];
    if (lane == 0) { wsum[wave] = ssum; wsq[wave] = ssq; }
    __syncthreads();

    float tot  = wsum[0] + wsum[1] + wsum[2] + wsum[3];
    float tot2 = wsq[0] + wsq[1] + wsq[2] + wsq[3];
    float mu   = tot * (1.0f / DMODEL);
    float var  = tot2 * (1.0f / DMODEL) - mu * mu;
    float rstd = rsqrtf(var + 1e-5f);

    float4 gm = *(const float4*)&gamma[tid * 4];
    float4 be = *(const float4*)&beta[tid * 4];
    float4 yo;
    yo.x = (xv.x - mu) * rstd * gm.x + be.x;
    yo.y = (xv.y - mu) * rstd * gm.y + be.y;
    yo.z = (xv.z - mu) * rstd * gm.z + be.z;
    yo.w = (xv.w - mu) * rstd * gm.w + be.w;
    *(float4*)&y[(size_t)row * DMODEL + tid * 4] = yo;
}

// ---------------------------------------------------------------------------
extern "C" void kernel_launch(void* const* d_in, const int* in_sizes, int n_in,
                              void* d_out, int out_size, void* d_ws, size_t ws_size,
                              hipStream_t stream) {
    const float* x     = (const float*)d_in[0];
    const float* state = (const float*)d_in[1];
    const float* Wqkv  = (const float*)d_in[2];
    const float* Wout  = (const float*)d_in[3];
    const float* gamma = (const float*)d_in[4];
    const float* beta  = (const float*)d_in[5];
    float* out = (float*)d_out;

    char* base = (char*)d_ws;
    // region A: qkv_raw f32 [0, 25.2MB); later overlaid by ah + res
    float*     qkv_raw = (float*)base;                        // S*3072 f32
    _Float16*  ah      = (_Float16*)base;                     // S*1024 f16 (4MB)
    float*     res     = (float*)(base + 8388608);            // S*1024 f32 (8MB)
    float*          qb  = (float*)(base + 25165824);          // H*S*64 f32
    unsigned short* khi = (unsigned short*)(base + 33554432); // H*S*64 bf16
    unsigned short* klo = (unsigned short*)(base + 37748736);
    unsigned short* vT  = (unsigned short*)(base + 41943040); // H*64*S bf16
    _Float16* WqkvT = (_Float16*)(base + 46137344);           // [3072][1024] f16
    _Float16* WoutT = (_Float16*)(base + 52428800);           // [1024][1024] f16
    _Float16* xh    = (_Float16*)(base + 54525952);           // [2048][1024] f16

    // --- prep: fp16 converts + weight transposes ---
    cvt_f16<<<(S_LEN * DMODEL) / 1024, 256, 0, stream>>>(x, xh);
    transpose_cvt<<<dim3(N_QKV / 32, DMODEL / 32), 256, 0, stream>>>(
        Wqkv, WqkvT, DMODEL, N_QKV);
    transpose_cvt<<<dim3(DMODEL / 32, DMODEL / 32), 256, 0, stream>>>(
        Wout, WoutT, DMODEL, DMODEL);

    // --- QKV projection: [2048,1024] x [1024,3072], 768 blocks = 3/CU ---
    gemm_f16<128, 64, 64, 32, false>
        <<<dim3(N_QKV / 64, S_LEN / 128), 256, 0, stream>>>(
            xh, WqkvT, nullptr, qkv_raw, S_LEN, N_QKV, DMODEL);

    // --- RoPE + scatter (q f32, k hi/lo bf16) ---
    rope_scatter<<<(S_LEN * DMODEL) / 256, 256, 0, stream>>>(qkv_raw, qb, khi, klo);

    // --- V transpose to [h][d][s] bf16 ---
    v_transpose<<<dim3(S_LEN / 64, NHEADS), 256, 0, stream>>>(qkv_raw, vT);

    // --- MFMA windowed attention (writes fp16 over dead qkv_raw) ---
    attn_mfma<<<dim3(S_LEN / 64, NHEADS), 256, 0, stream>>>(
        qb, khi, klo, vT, ah);

    // --- out projection + residual: [2048,1024] x [1024,1024] + x, 512 blocks ---
    gemm_f16<64, 64, 32, 32, true>
        <<<dim3(DMODEL / 64, S_LEN / 64), 256, 0, stream>>>(
            ah, WoutT, x, res, S_LEN, DMODEL, DMODEL);

    // --- LayerNorm ---
    layernorm_k<<<S_LEN, 256, 0, stream>>>(res, gamma, beta, out);

    // --- state passthrough ---
    hipMemcpyAsync(out + (size_t)S_LEN * DMODEL, state,
                   (size_t)DMODEL * sizeof(float),
                   hipMemcpyDeviceToDevice, stream);
}